// Round 2
// baseline (325.623 us; speedup 1.0000x reference)
//
#include <hip/hip_runtime.h>
#include <cstdint>
#include <cstddef>

// ---------------------------------------------------------------------------
// NAMAttention. Round 2: both big GEMMs (fused QKV+w/r projection, output
// projection) moved to the 256x256 8-phase pipelined MFMA template:
//   - BM=BN=256, BK=64, 512 thr (8 waves, 2Mx4N), LDS 128 KiB (2 dbuf x
//     2 quadrant-aligned halves x 128x64 x {A,B}).
//   - counted s_waitcnt vmcnt(4) at phases 4/8 only (T3+T4), raw s_barrier,
//     s_setprio around MFMA cluster (T5), XOR 16B-chunk swizzle (T2),
//     bijective XCD blockIdx swizzle (T1).
// Sync ledger (verified): stage slots ph1..8 = {B1.Ah1,B1.Bh1,B0.Ah0,B0.Bh0,
// B0.Ah1,B0.Bh1,B1'.Ah0,B1'.Bh0}; quadrant order per K-step (mh,nv)=
// (0,0),(0,1),(1,0),(1,1); A-half h holds rows {wm*128+h*64+j}, B-half h holds
// rows {wn*64+h*32+j} -> every region's last read is >=1 barrier before its
// re-stage slot; vmcnt(4)+barrier at ph4/ph8 makes staged halves visible
// cross-wave before first read.
// ---------------------------------------------------------------------------

typedef __bf16 bf16x8 __attribute__((ext_vector_type(8)));
typedef float  f32x4  __attribute__((ext_vector_type(4)));
typedef unsigned short u16x8 __attribute__((ext_vector_type(8)));
typedef unsigned short u16x4 __attribute__((ext_vector_type(4)));

#define ROWS 16384      // S*B
#define DM   1024
#define NPACK 3328      // padded packed-N (3104 used, 13 tiles of 256)

__device__ __forceinline__ unsigned short f2bf(float f) {
  unsigned int u = __builtin_bit_cast(unsigned int, f);
  u += 0x7FFFu + ((u >> 16) & 1u);            // round-to-nearest-even
  return (unsigned short)(u >> 16);
}
__device__ __forceinline__ float bf2f(unsigned short h) {
  unsigned int u = ((unsigned int)h) << 16;
  return __builtin_bit_cast(float, u);
}
__device__ __forceinline__ float sigm(float x) { return 1.0f / (1.0f + __expf(-x)); }

__device__ __forceinline__ void gload_lds16(const void* g, void* l) {
  __builtin_amdgcn_global_load_lds((__attribute__((address_space(1))) void*)(g),
                                   (__attribute__((address_space(3))) void*)(l),
                                   16, 0, 0);
}

// ---------------- cast input to bf16 ----------------
__global__ __launch_bounds__(256) void k_cast_x(const float* __restrict__ X,
                                                unsigned short* __restrict__ Xb) {
  size_t i = ((size_t)blockIdx.x * 256 + threadIdx.x) * 8;
  f32x4 a = *(const f32x4*)(X + i);
  f32x4 b = *(const f32x4*)(X + i + 4);
  u16x8 o;
  o[0] = f2bf(a[0]); o[1] = f2bf(a[1]); o[2] = f2bf(a[2]); o[3] = f2bf(a[3]);
  o[4] = f2bf(b[0]); o[5] = f2bf(b[1]); o[6] = f2bf(b[2]); o[7] = f2bf(b[3]);
  *(u16x8*)(Xb + i) = o;
}

// ---------------- pack weights (bf16) + packed bias ----------------
// Wpack rows: [0,1024) Wq | [1024,2048) Wk | [2048,3072) Wv | [3072,3088) Ww
//             | [3088,3104) Wr | [3104,3328) zeros.   Wob: Wo (1024 rows).
__global__ __launch_bounds__(256) void k_pack_w(
    const float* __restrict__ Wq, const float* __restrict__ Wk, const float* __restrict__ Wv,
    const float* __restrict__ Wo, const float* __restrict__ Ww, const float* __restrict__ Wr,
    const float* __restrict__ bq, const float* __restrict__ bk, const float* __restrict__ bv,
    const float* __restrict__ bw, const float* __restrict__ br,
    unsigned short* __restrict__ Wpack, float* __restrict__ biasP,
    unsigned short* __restrict__ Wob) {
  int r = blockIdx.x, t = threadIdx.x;
  const float* src; float bias = 0.0f; unsigned short* dst;
  if (r < 1024)      { src = Wq + (size_t)r * DM;          bias = bq[r];        dst = Wpack + (size_t)r * DM; }
  else if (r < 2048) { src = Wk + (size_t)(r - 1024) * DM; bias = bk[r - 1024]; dst = Wpack + (size_t)r * DM; }
  else if (r < 3072) { src = Wv + (size_t)(r - 2048) * DM; bias = bv[r - 2048]; dst = Wpack + (size_t)r * DM; }
  else if (r < 3088) { src = Ww + (size_t)(r - 3072) * DM; bias = bw[r - 3072]; dst = Wpack + (size_t)r * DM; }
  else if (r < 3104) { src = Wr + (size_t)(r - 3088) * DM; bias = br[r - 3088]; dst = Wpack + (size_t)r * DM; }
  else if (r < 3328) { src = nullptr;                                           dst = Wpack + (size_t)r * DM; }
  else               { src = Wo + (size_t)(r - 3328) * DM;                      dst = Wob + (size_t)(r - 3328) * DM; }
  int c = t * 4;
  u16x4 o;
  if (src) {
    f32x4 v = *(const f32x4*)(src + c);
    o[0] = f2bf(v[0]); o[1] = f2bf(v[1]); o[2] = f2bf(v[2]); o[3] = f2bf(v[3]);
  } else {
    o[0] = 0; o[1] = 0; o[2] = 0; o[3] = 0;
  }
  *(u16x4*)(dst + c) = o;
  if (t == 0 && r < NPACK) biasP[r] = bias;
}

// ============================ 256x256 8-phase core ==========================
// LDS element layout (bf16): A at [P*16384 + H*8192 + idx*64 + col],
// B at 32768 + same. Within a half-buffer, 16B chunk j of row idx holds
// global chunk j ^ (idx&7) (T2 swizzle; idx&7 == lane-derived on both sides).

__device__ __forceinline__ void stage_a(const unsigned short* __restrict__ Ag, int m0, int kt,
                                        __bf16* sm, int P, int H, int lane, int w) {
#pragma unroll
  for (int e = 0; e < 2; ++e) {
    int i  = e * 64 + w * 8 + (lane >> 3);
    int jp = (lane & 7) ^ (lane >> 3);
    int grow = m0 + ((i >> 6) << 7) + H * 64 + (i & 63);
    gload_lds16(Ag + (size_t)grow * DM + kt + jp * 8,
                (void*)(sm + P * 16384 + H * 8192 + (e * 64 + w * 8) * 64));
  }
}
__device__ __forceinline__ void stage_b(const unsigned short* __restrict__ Bg, int n0, int kt,
                                        __bf16* sm, int P, int H, int lane, int w) {
#pragma unroll
  for (int e = 0; e < 2; ++e) {
    int i  = e * 64 + w * 8 + (lane >> 3);
    int jp = (lane & 7) ^ (lane >> 3);
    int grow = n0 + ((i >> 5) << 6) + H * 32 + (i & 31);
    gload_lds16(Bg + (size_t)grow * DM + kt + jp * 8,
                (void*)(sm + 32768 + P * 16384 + H * 8192 + (e * 64 + w * 8) * 64));
  }
}

// One phase: ds_read quadrant frags -> stage one half-tile -> barrier ->
// lgkmcnt(0) -> setprio(1) 16 MFMA setprio(0) -> [vmcnt(N)] -> barrier.
#define QPHASE(P, MH, NV, RDA, RDB, STG, VM)                                       \
  do {                                                                             \
    if (RDA) {                                                                     \
      _Pragma("unroll") for (int mi = 0; mi < 4; ++mi)                             \
      _Pragma("unroll") for (int ks = 0; ks < 2; ++ks)                             \
        fa[mi][ks] = *(const bf16x8*)(sm + (P)*16384 + (MH)*8192                   \
            + (wm * 64 + mi * 16 + l15) * 64 + (((ks * 4 + l4) ^ l7) << 3));       \
    }                                                                              \
    if (RDB) {                                                                     \
      _Pragma("unroll") for (int ni = 0; ni < 2; ++ni)                             \
      _Pragma("unroll") for (int ks = 0; ks < 2; ++ks)                             \
        fb[NV][ni][ks] = *(const bf16x8*)(sm + 32768 + (P)*16384 + (NV)*8192       \
            + (wn * 32 + ni * 16 + l15) * 64 + (((ks * 4 + l4) ^ l7) << 3));       \
    }                                                                              \
    STG;                                                                           \
    __builtin_amdgcn_s_barrier();                                                  \
    asm volatile("s_waitcnt lgkmcnt(0)" ::: "memory");                             \
    __builtin_amdgcn_sched_barrier(0);                                             \
    __builtin_amdgcn_s_setprio(1);                                                 \
    _Pragma("unroll") for (int ks = 0; ks < 2; ++ks)                               \
    _Pragma("unroll") for (int mi = 0; mi < 4; ++mi)                               \
    _Pragma("unroll") for (int ni = 0; ni < 2; ++ni)                               \
      acc[(MH)*4 + mi][(NV)*2 + ni] = __builtin_amdgcn_mfma_f32_16x16x32_bf16(     \
          fa[mi][ks], fb[NV][ni][ks], acc[(MH)*4 + mi][(NV)*2 + ni], 0, 0, 0);     \
    __builtin_amdgcn_s_setprio(0);                                                 \
    if ((VM) == 4) {                                                               \
      __builtin_amdgcn_sched_barrier(0);                                           \
      asm volatile("s_waitcnt vmcnt(4)" ::: "memory");                             \
    }                                                                              \
    if ((VM) == 0) {                                                               \
      __builtin_amdgcn_sched_barrier(0);                                           \
      asm volatile("s_waitcnt vmcnt(0)" ::: "memory");                             \
    }                                                                              \
    __builtin_amdgcn_s_barrier();                                                  \
    __builtin_amdgcn_sched_barrier(0);                                             \
  } while (0)

__device__ __forceinline__ void gemm256(const unsigned short* __restrict__ Ag,
                                        const unsigned short* __restrict__ Bg,
                                        __bf16* sm, f32x4 (&acc)[8][4],
                                        int m0, int n0, int lane, int w) {
  const int wm = w >> 2, wn = w & 3;
  const int l15 = lane & 15, l4 = lane >> 4, l7 = lane & 7;
  bf16x8 fa[4][2];        // A frags of current mh-half
  bf16x8 fb[2][2][2];     // B frags, both nv-halves kept live per K-step
  // ---- prologue: t=0 full (buf0) + t=1 Ah0,Bh0 (buf1) ----
  stage_a(Ag, m0, 0, sm, 0, 0, lane, w);
  stage_a(Ag, m0, 0, sm, 0, 1, lane, w);
  stage_b(Bg, n0, 0, sm, 0, 0, lane, w);
  stage_b(Bg, n0, 0, sm, 0, 1, lane, w);
  stage_a(Ag, m0, 64, sm, 1, 0, lane, w);
  stage_b(Bg, n0, 64, sm, 1, 0, lane, w);
  asm volatile("s_waitcnt vmcnt(4)" ::: "memory");   // buf0 landed
  __builtin_amdgcn_s_barrier();
  __builtin_amdgcn_sched_barrier(0);
  // ---- steady state: 7 iters x (t0=2i from buf0, t1=2i+1 from buf1) ----
  for (int it = 0; it < 7; ++it) {
    int kt1 = (2 * it + 1) * 64, kt2 = (2 * it + 2) * 64, kt3 = (2 * it + 3) * 64;
    QPHASE(0, 0, 0, 1, 1, stage_a(Ag, m0, kt1, sm, 1, 1, lane, w), -1);
    QPHASE(0, 0, 1, 0, 1, stage_b(Bg, n0, kt1, sm, 1, 1, lane, w), -1);
    QPHASE(0, 1, 0, 1, 0, stage_a(Ag, m0, kt2, sm, 0, 0, lane, w), -1);
    QPHASE(0, 1, 1, 0, 0, stage_b(Bg, n0, kt2, sm, 0, 0, lane, w),  4);
    QPHASE(1, 0, 0, 1, 1, stage_a(Ag, m0, kt2, sm, 0, 1, lane, w), -1);
    QPHASE(1, 0, 1, 0, 1, stage_b(Bg, n0, kt2, sm, 0, 1, lane, w), -1);
    QPHASE(1, 1, 0, 1, 0, stage_a(Ag, m0, kt3, sm, 1, 0, lane, w), -1);
    QPHASE(1, 1, 1, 0, 0, stage_b(Bg, n0, kt3, sm, 1, 0, lane, w),  4);
  }
  // ---- tail: t=14 (buf0), t=15 (buf1); finish t=15 staging, then drain ----
  QPHASE(0, 0, 0, 1, 1, stage_a(Ag, m0, 960, sm, 1, 1, lane, w), -1);
  QPHASE(0, 0, 1, 0, 1, stage_b(Bg, n0, 960, sm, 1, 1, lane, w), -1);
  QPHASE(0, 1, 0, 1, 0, (void)0, -1);
  QPHASE(0, 1, 1, 0, 0, (void)0,  0);
  QPHASE(1, 0, 0, 1, 1, (void)0, -1);
  QPHASE(1, 0, 1, 0, 1, (void)0, -1);
  QPHASE(1, 1, 0, 1, 0, (void)0, -1);
  QPHASE(1, 1, 1, 0, 0, (void)0, -1);
}

// ---------------- fused QKV + w/r logits GEMM (256x256, 8-phase) ----------------
__global__ __launch_bounds__(512, 2) void k_gemm_qkv2(
    const unsigned short* __restrict__ Xb, const unsigned short* __restrict__ Wpack,
    const float* __restrict__ biasP,
    unsigned short* __restrict__ Qb, unsigned short* __restrict__ Kb,
    unsigned short* __restrict__ Vb, float* __restrict__ WRf) {
  __shared__ __bf16 sm[65536];                 // 128 KiB
  int t = threadIdx.x, lane = t & 63, w = t >> 6;
  int orig = blockIdx.x;
  int wg = (orig & 7) * 104 + (orig >> 3);     // bijective XCD swizzle (832 = 8*104)
  int m0 = (wg & 63) << 8, n0 = (wg >> 6) << 8;
  f32x4 acc[8][4];
#pragma unroll
  for (int i = 0; i < 8; ++i)
#pragma unroll
    for (int j = 0; j < 4; ++j) acc[i][j] = (f32x4){0.f, 0.f, 0.f, 0.f};
  gemm256(Xb, Wpack, sm, acc, m0, n0, lane, w);
  const int wm = w >> 2, wn = w & 3, l15 = lane & 15, l4 = lane >> 4;
  float bb[2][2];
#pragma unroll
  for (int nv = 0; nv < 2; ++nv)
#pragma unroll
    for (int ni = 0; ni < 2; ++ni) bb[nv][ni] = biasP[n0 + wn * 64 + nv * 32 + ni * 16 + l15];
#pragma unroll
  for (int mh = 0; mh < 2; ++mh)
#pragma unroll
    for (int mi = 0; mi < 4; ++mi)
#pragma unroll
      for (int e = 0; e < 4; ++e) {
        int row = m0 + wm * 128 + mh * 64 + mi * 16 + 4 * l4 + e;
#pragma unroll
        for (int nv = 0; nv < 2; ++nv)
#pragma unroll
          for (int ni = 0; ni < 2; ++ni) {
            int col = n0 + wn * 64 + nv * 32 + ni * 16 + l15;
            float v = acc[mh * 4 + mi][nv * 2 + ni][e] + bb[nv][ni];
            if (col < 1024)      Qb[(size_t)row * DM + col] = f2bf(v);
            else if (col < 2048) Kb[(size_t)row * DM + col - 1024] = f2bf(v);
            else if (col < 3072) Vb[(size_t)row * DM + col - 2048] = f2bf(v);
            else if (col < 3104) WRf[(size_t)row * 32 + col - 3072] = v;
          }
      }
}

// ---------------- final projection: Out = Ob @ Wo^T + bo (256x256, 8-phase) ------
__global__ __launch_bounds__(512, 2) void k_gemm_out2(
    const unsigned short* __restrict__ Ob, const unsigned short* __restrict__ Wob,
    const float* __restrict__ bo, float* __restrict__ Out) {
  __shared__ __bf16 sm[65536];
  int t = threadIdx.x, lane = t & 63, w = t >> 6;
  int orig = blockIdx.x;
  int wg = (orig & 7) * 32 + (orig >> 3);      // 256 = 8*32
  int m0 = (wg & 63) << 8, n0 = (wg >> 6) << 8;
  f32x4 acc[8][4];
#pragma unroll
  for (int i = 0; i < 8; ++i)
#pragma unroll
    for (int j = 0; j < 4; ++j) acc[i][j] = (f32x4){0.f, 0.f, 0.f, 0.f};
  gemm256(Ob, Wob, sm, acc, m0, n0, lane, w);
  const int wm = w >> 2, wn = w & 3, l15 = lane & 15, l4 = lane >> 4;
  float bb[2][2];
#pragma unroll
  for (int nv = 0; nv < 2; ++nv)
#pragma unroll
    for (int ni = 0; ni < 2; ++ni) bb[nv][ni] = bo[n0 + wn * 64 + nv * 32 + ni * 16 + l15];
#pragma unroll
  for (int mh = 0; mh < 2; ++mh)
#pragma unroll
    for (int mi = 0; mi < 4; ++mi)
#pragma unroll
      for (int e = 0; e < 4; ++e) {
        int row = m0 + wm * 128 + mh * 64 + mi * 16 + 4 * l4 + e;
#pragma unroll
        for (int nv = 0; nv < 2; ++nv)
#pragma unroll
          for (int ni = 0; ni < 2; ++ni) {
            int col = n0 + wn * 64 + nv * 32 + ni * 16 + l15;
            Out[(size_t)row * DM + col] = acc[mh * 4 + mi][nv * 2 + ni][e] + bb[nv][ni];
          }
      }
}

// ---------------- per-head normalize q,k ; v *= sigmoid(w) ----------------
__global__ __launch_bounds__(256) void k_postproc(unsigned short* __restrict__ Qb,
                                                  unsigned short* __restrict__ Kb,
                                                  unsigned short* __restrict__ Vb,
                                                  const float* __restrict__ WRf) {
  int row = blockIdx.x, t = threadIdx.x;
  unsigned short* base; int tt;
  if (t < 128) { base = Qb; tt = t; } else { base = Kb; tt = t - 128; }
  size_t off = (size_t)row * DM + tt * 8;
  u16x8 v = *(const u16x8*)(base + off);
  float f[8]; float ssq = 0.f;
#pragma unroll
  for (int e = 0; e < 8; e++) { f[e] = bf2f(v[e]); ssq += f[e] * f[e]; }
  ssq += __shfl_xor(ssq, 1);
  ssq += __shfl_xor(ssq, 2);
  ssq += __shfl_xor(ssq, 4);          // 8 lanes = one 64-elem head
  float scale = 1.0f / fmaxf(sqrtf(ssq), 1e-12f);
  u16x8 o;
#pragma unroll
  for (int e = 0; e < 8; e++) o[e] = f2bf(f[e] * scale);
  *(u16x8*)(base + off) = o;
  if (t < 128) {
    int h = t >> 3;
    float w = sigm(WRf[(size_t)row * 32 + h]);
    size_t voff = (size_t)row * DM + t * 8;
    u16x8 vv = *(const u16x8*)(Vb + voff);
    u16x8 ov;
#pragma unroll
    for (int e = 0; e < 8; e++) ov[e] = f2bf(bf2f(vv[e]) * w);
    *(u16x8*)(Vb + voff) = ov;
  }
}

// ---------------- A[b,n,i,j] = sum_s vw[s,(b,n),i] * khat[s,(b,n),j] ----------------
__global__ __launch_bounds__(256, 2) void k_gemm_A(const unsigned short* __restrict__ Kb,
                                                   const unsigned short* __restrict__ Vb,
                                                   float* __restrict__ Aout,
                                                   unsigned short* __restrict__ Abf) {
  __shared__ __bf16 sK[64 * 64];
  __shared__ __bf16 sV[64 * 64];
  int t = threadIdx.x, lane = t & 63, wid = t >> 6;
  int bn = blockIdx.x;             // b*16 + n
  int b = bn >> 4, n = bn & 15;
  f32x4 acc[4];
#pragma unroll
  for (int j = 0; j < 4; j++) acc[j] = (f32x4){0.f, 0.f, 0.f, 0.f};
  int lrow = lane >> 3, lcol = (lane & 7) * 8;

  for (int st = 0; st < 2048; st += 64) {
#pragma unroll
    for (int c = 0; c < 2; c++) {
      int r0 = wid * 16 + c * 8;
      size_t g = ((size_t)(st + r0 + lrow) * 8 + b) * DM + n * 64 + lcol;
      gload_lds16(Kb + g, (void*)(sK + r0 * 64));
      gload_lds16(Vb + g, (void*)(sV + r0 * 64));
    }
    __syncthreads();
#pragma unroll
    for (int kk = 0; kk < 64; kk += 32) {
      bf16x8 av, bv[4];
#pragma unroll
      for (int e = 0; e < 8; e++)
        av[e] = sV[(kk + 8 * (lane >> 4) + e) * 64 + wid * 16 + (lane & 15)];
#pragma unroll
      for (int jn = 0; jn < 4; jn++)
#pragma unroll
        for (int e = 0; e < 8; e++)
          bv[jn][e] = sK[(kk + 8 * (lane >> 4) + e) * 64 + jn * 16 + (lane & 15)];
#pragma unroll
      for (int jn = 0; jn < 4; jn++)
        acc[jn] = __builtin_amdgcn_mfma_f32_16x16x32_bf16(av, bv[jn], acc[jn], 0, 0, 0);
    }
    __syncthreads();
  }
  float* Ao = Aout + (size_t)bn * 4096;
  unsigned short* Ab = Abf + (size_t)bn * 4096;
#pragma unroll
  for (int jn = 0; jn < 4; jn++) {
#pragma unroll
    for (int e = 0; e < 4; e++) {
      int i = wid * 16 + 4 * (lane >> 4) + e;
      int j = jn * 16 + (lane & 15);
      Ao[i * 64 + j] = acc[jn][e];
      Ab[i * 64 + j] = f2bf(acc[jn][e]);
    }
  }
}

// ---------------- out2[row, n*64+i] = r * sum_j qhat[row, n*64+j]*A[bn,i,j] ----------------
__global__ __launch_bounds__(256, 2) void k_gemm_o2(const unsigned short* __restrict__ Qb,
                                                    const unsigned short* __restrict__ Abf,
                                                    const float* __restrict__ WRf,
                                                    unsigned short* __restrict__ Ob) {
  __shared__ __bf16 sQ[128 * 64];
  __shared__ __bf16 sA[64 * 64];
  int t = threadIdx.x, lane = t & 63, wid = t >> 6;
  int bn = blockIdx.x & 127, stile = blockIdx.x >> 7;
  int b = bn >> 4, n = bn & 15;
  int s0 = stile * 128;
  int lrow = lane >> 3, lcol = (lane & 7) * 8;
#pragma unroll
  for (int c = 0; c < 4; c++) {
    int r0 = wid * 32 + c * 8;
    gload_lds16(Qb + ((size_t)(s0 + r0 + lrow) * 8 + b) * DM + n * 64 + lcol,
                (void*)(sQ + r0 * 64));
  }
#pragma unroll
  for (int c = 0; c < 2; c++) {
    int r0 = wid * 16 + c * 8;
    gload_lds16(Abf + (size_t)bn * 4096 + (size_t)(r0 + lrow) * 64 + lcol,
                (void*)(sA + r0 * 64));
  }
  __syncthreads();
  f32x4 acc[2][4];
#pragma unroll
  for (int i = 0; i < 2; i++)
#pragma unroll
    for (int j = 0; j < 4; j++) acc[i][j] = (f32x4){0.f, 0.f, 0.f, 0.f};
#pragma unroll
  for (int kk = 0; kk < 64; kk += 32) {
    bf16x8 aq[2], bA[4];
#pragma unroll
    for (int mi = 0; mi < 2; mi++)
      aq[mi] = *(const bf16x8*)(sQ + (wid * 32 + mi * 16 + (lane & 15)) * 64 + kk + 8 * (lane >> 4));
#pragma unroll
    for (int ni = 0; ni < 4; ni++)
      bA[ni] = *(const bf16x8*)(sA + (ni * 16 + (lane & 15)) * 64 + kk + 8 * (lane >> 4));
#pragma unroll
    for (int mi = 0; mi < 2; mi++)
#pragma unroll
      for (int ni = 0; ni < 4; ni++)
        acc[mi][ni] = __builtin_amdgcn_mfma_f32_16x16x32_bf16(aq[mi], bA[ni], acc[mi][ni], 0, 0, 0);
  }
#pragma unroll
  for (int mi = 0; mi < 2; mi++) {
#pragma unroll
    for (int e = 0; e < 4; e++) {
      int srow = wid * 32 + mi * 16 + 4 * (lane >> 4) + e;
      size_t row = (size_t)(s0 + srow) * 8 + b;
      float rv = sigm(WRf[row * 32 + 16 + n]);
#pragma unroll
      for (int ni = 0; ni < 4; ni++)
        Ob[row * DM + n * 64 + ni * 16 + (lane & 15)] = f2bf(acc[mi][ni][e] * rv);
    }
  }
}

// ---------------------------------------------------------------------------
extern "C" void kernel_launch(void* const* d_in, const int* in_sizes, int n_in,
                              void* d_out, int out_size, void* d_ws, size_t ws_size,
                              hipStream_t stream) {
  (void)in_sizes; (void)n_in; (void)out_size; (void)ws_size;
  const float* X  = (const float*)d_in[0];
  const float* Wq = (const float*)d_in[1];  const float* bq = (const float*)d_in[2];
  const float* Wk = (const float*)d_in[3];  const float* bk = (const float*)d_in[4];
  const float* Wv = (const float*)d_in[5];  const float* bv = (const float*)d_in[6];
  const float* Wo = (const float*)d_in[7];  const float* bo = (const float*)d_in[8];
  const float* Ww = (const float*)d_in[9];  const float* bw = (const float*)d_in[10];
  const float* Wr = (const float*)d_in[11]; const float* br = (const float*)d_in[12];

  char* ws = (char*)d_ws;
  // Abf aliases Wpack (dead after qkv2); Ob aliases Xb (dead after qkv2).
  unsigned short* Wpack = (unsigned short*)(ws + 0);            // 3328*1024*2 = 6,815,744
  unsigned short* Abf   = (unsigned short*)(ws + 0);
  float*          biasP = (float*)(ws + 6815744);               // 13,312
  unsigned short* Wob   = (unsigned short*)(ws + 6829056);      // 2,097,152
  unsigned short* Xb    = (unsigned short*)(ws + 8926208);      // 33,554,432
  unsigned short* Ob    = Xb;
  unsigned short* Qb    = (unsigned short*)(ws + 42480640);     // 33,554,432
  unsigned short* Kb    = (unsigned short*)(ws + 76035072);     // 33,554,432
  unsigned short* Vb    = (unsigned short*)(ws + 109589504);    // 33,554,432
  float*          WRf   = (float*)(ws + 143143936);             // 2,097,152 -> 145,241,088

  float* Out0 = (float*)d_out;
  float* Aout = Out0 + (size_t)ROWS * DM;   // second tuple output

  k_cast_x<<<dim3(8192), dim3(256), 0, stream>>>(X, Xb);
  k_pack_w<<<dim3(4352), dim3(256), 0, stream>>>(Wq, Wk, Wv, Wo, Ww, Wr,
                                                 bq, bk, bv, bw, br, Wpack, biasP, Wob);
  k_gemm_qkv2<<<dim3(832), dim3(512), 0, stream>>>(Xb, Wpack, biasP, Qb, Kb, Vb, WRf);
  k_postproc<<<dim3(ROWS), dim3(256), 0, stream>>>(Qb, Kb, Vb, WRf);
  k_gemm_A<<<dim3(128), dim3(256), 0, stream>>>(Kb, Vb, Aout, Abf);
  k_gemm_o2<<<dim3(2048), dim3(256), 0, stream>>>(Qb, Abf, WRf, Ob);
  k_gemm_out2<<<dim3(256), dim3(512), 0, stream>>>(Ob, Wob, bo, Out0);
}

// Round 3
// 250.066 us; speedup vs baseline: 1.3021x; 1.3021x over previous
//
#include <hip/hip_runtime.h>
#include <cstdint>
#include <cstddef>

// ---------------------------------------------------------------------------
// NAMAttention round 3:
//  - qkv GEMM: 256x256 tile, BK=64, 2-phase loop (stage-next -> ds_read ->
//    64 MFMA -> __syncthreads), both-sides XOR chunk swizzle, XCD swizzle.
//    N=3072 exactly (Q|K|V); fused epilogue: per-head L2-norm of q,k (fp32,
//    in-register via shfl_xor over 16-lane row groups) and V *= sigm(w).
//  - w/r logits: tiny dedicated MFMA kernel (16384x32x1024) before qkv.
//  - gemm_A: split-K=2 + reduce kernel.
//  - o2 / out-proj / cast: round-1 measured-good versions.
// ---------------------------------------------------------------------------

typedef __bf16 bf16x8 __attribute__((ext_vector_type(8)));
typedef float  f32x4  __attribute__((ext_vector_type(4)));
typedef unsigned short u16x8 __attribute__((ext_vector_type(8)));
typedef unsigned short u16x4 __attribute__((ext_vector_type(4)));

#define ROWS 16384      // S*B
#define DM   1024

__device__ __forceinline__ unsigned short f2bf(float f) {
  unsigned int u = __builtin_bit_cast(unsigned int, f);
  u += 0x7FFFu + ((u >> 16) & 1u);            // round-to-nearest-even
  return (unsigned short)(u >> 16);
}
__device__ __forceinline__ float bf2f(unsigned short h) {
  unsigned int u = ((unsigned int)h) << 16;
  return __builtin_bit_cast(float, u);
}
__device__ __forceinline__ float sigm(float x) { return 1.0f / (1.0f + __expf(-x)); }

__device__ __forceinline__ void gload_lds16(const void* g, void* l) {
  __builtin_amdgcn_global_load_lds((__attribute__((address_space(1))) void*)(g),
                                   (__attribute__((address_space(3))) void*)(l),
                                   16, 0, 0);
}

// ---------------- cast input to bf16 ----------------
__global__ __launch_bounds__(256) void k_cast_x(const float* __restrict__ X,
                                                unsigned short* __restrict__ Xb) {
  size_t i = ((size_t)blockIdx.x * 256 + threadIdx.x) * 8;
  f32x4 a = *(const f32x4*)(X + i);
  f32x4 b = *(const f32x4*)(X + i + 4);
  u16x8 o;
  o[0] = f2bf(a[0]); o[1] = f2bf(a[1]); o[2] = f2bf(a[2]); o[3] = f2bf(a[3]);
  o[4] = f2bf(b[0]); o[5] = f2bf(b[1]); o[6] = f2bf(b[2]); o[7] = f2bf(b[3]);
  *(u16x8*)(Xb + i) = o;
}

// ---------------- pack weights (bf16) + biases ----------------
// Wpack rows [0,3072): Wq|Wk|Wv.  WRw rows [0,32): Ww|Wr.  Wob: Wo.
__global__ __launch_bounds__(256) void k_pack_w(
    const float* __restrict__ Wq, const float* __restrict__ Wk, const float* __restrict__ Wv,
    const float* __restrict__ Wo, const float* __restrict__ Ww, const float* __restrict__ Wr,
    const float* __restrict__ bq, const float* __restrict__ bk, const float* __restrict__ bv,
    const float* __restrict__ bw, const float* __restrict__ br,
    unsigned short* __restrict__ Wpack, float* __restrict__ biasP,
    unsigned short* __restrict__ WRw, float* __restrict__ biasWR,
    unsigned short* __restrict__ Wob) {
  int r = blockIdx.x, t = threadIdx.x;
  const float* src; float bias = 0.0f; unsigned short* dst; float* bdst;
  if (r < 1024)      { src = Wq + (size_t)r * DM;          bias = bq[r];        dst = Wpack + (size_t)r * DM;          bdst = biasP + r; }
  else if (r < 2048) { src = Wk + (size_t)(r - 1024) * DM; bias = bk[r - 1024]; dst = Wpack + (size_t)r * DM;          bdst = biasP + r; }
  else if (r < 3072) { src = Wv + (size_t)(r - 2048) * DM; bias = bv[r - 2048]; dst = Wpack + (size_t)r * DM;          bdst = biasP + r; }
  else if (r < 3088) { src = Ww + (size_t)(r - 3072) * DM; bias = bw[r - 3072]; dst = WRw + (size_t)(r - 3072) * DM;   bdst = biasWR + (r - 3072); }
  else if (r < 3104) { src = Wr + (size_t)(r - 3088) * DM; bias = br[r - 3088]; dst = WRw + (size_t)(r - 3072) * DM;   bdst = biasWR + (r - 3072); }
  else               { src = Wo + (size_t)(r - 3104) * DM;                      dst = Wob + (size_t)(r - 3104) * DM;   bdst = nullptr; }
  int c = t * 4;
  f32x4 v = *(const f32x4*)(src + c);
  u16x4 o;
  o[0] = f2bf(v[0]); o[1] = f2bf(v[1]); o[2] = f2bf(v[2]); o[3] = f2bf(v[3]);
  *(u16x4*)(dst + c) = o;
  if (t == 0 && bdst) *bdst = bias;
}

// ---------------- w/r logits: WRf[row,0..31] = X @ [Ww;Wr]^T + b ----------------
__global__ __launch_bounds__(256) void k_wr(const unsigned short* __restrict__ Xb,
                                            const unsigned short* __restrict__ WRw,
                                            const float* __restrict__ biasWR,
                                            float* __restrict__ WRf) {
  __shared__ __bf16 sA[128 * 64];
  __shared__ __bf16 sB[32 * 64];
  int t = threadIdx.x, lane = t & 63, wid = t >> 6;
  int m0 = blockIdx.x * 128;
  int l15 = lane & 15, l4 = lane >> 4;
  f32x4 acc[2][2];
#pragma unroll
  for (int i = 0; i < 2; ++i)
#pragma unroll
    for (int j = 0; j < 2; ++j) acc[i][j] = (f32x4){0.f, 0.f, 0.f, 0.f};
  int srow = t >> 3, schunk = (t & 7) * 8;
  for (int kt = 0; kt < DM; kt += 64) {
#pragma unroll
    for (int c = 0; c < 4; ++c)
      gload_lds16(Xb + (size_t)(m0 + c * 32 + srow) * DM + kt + schunk,
                  (void*)(sA + c * 2048 + wid * 512));
    gload_lds16(WRw + (size_t)srow * DM + kt + schunk, (void*)(sB + wid * 512));
    __syncthreads();
#pragma unroll
    for (int ks = 0; ks < 2; ++ks) {
      bf16x8 fa[2], fb[2];
#pragma unroll
      for (int mi = 0; mi < 2; ++mi)
        fa[mi] = *(const bf16x8*)(sA + (wid * 32 + mi * 16 + l15) * 64 + (ks * 4 + l4) * 8);
#pragma unroll
      for (int ni = 0; ni < 2; ++ni)
        fb[ni] = *(const bf16x8*)(sB + (ni * 16 + l15) * 64 + (ks * 4 + l4) * 8);
#pragma unroll
      for (int mi = 0; mi < 2; ++mi)
#pragma unroll
        for (int ni = 0; ni < 2; ++ni)
          acc[mi][ni] = __builtin_amdgcn_mfma_f32_16x16x32_bf16(fa[mi], fb[ni], acc[mi][ni], 0, 0, 0);
    }
    __syncthreads();
  }
#pragma unroll
  for (int mi = 0; mi < 2; ++mi)
#pragma unroll
    for (int e = 0; e < 4; ++e) {
      int row = m0 + wid * 32 + mi * 16 + 4 * l4 + e;
#pragma unroll
      for (int ni = 0; ni < 2; ++ni)
        WRf[(size_t)row * 32 + ni * 16 + l15] = acc[mi][ni][e] + biasWR[ni * 16 + l15];
    }
}

// ---------------- fused QKV GEMM: 256x256 tile, 2-phase, fused norm/gating ------
__global__ __launch_bounds__(512, 2) void k_gemm_qkv3(
    const unsigned short* __restrict__ Xb, const unsigned short* __restrict__ Wpack,
    const float* __restrict__ biasP, const float* __restrict__ WRf,
    unsigned short* __restrict__ Qb, unsigned short* __restrict__ Kb,
    unsigned short* __restrict__ Vb) {
  __shared__ __bf16 sm[65536];            // [P][{A:16384,B:16384}] elements
  const int t = threadIdx.x, lane = t & 63, w = t >> 6;
  const int wm = w >> 2, wn = w & 3;
  const int l15 = lane & 15, l4 = lane >> 4, l7 = lane & 7;
  int orig = blockIdx.x;
  int wg = (orig & 7) * 96 + (orig >> 3);          // bijective XCD swizzle, 768=8*96
  const int m0 = (wg & 63) << 8;                   // 64 m-tiles
  const int n0 = (wg >> 6) << 8;                   // 12 n-tiles

  const int srow = t >> 3;                         // 0..63
  const int schunk = ((t & 7) ^ (srow & 7)) * 8;   // swizzled source chunk
  const unsigned short* Asrc = Xb + (size_t)(m0 + srow) * DM + schunk;
  const unsigned short* Bsrc = Wpack + (size_t)(n0 + srow) * DM + schunk;

  f32x4 acc[8][4];
#pragma unroll
  for (int i = 0; i < 8; ++i)
#pragma unroll
    for (int j = 0; j < 4; ++j) acc[i][j] = (f32x4){0.f, 0.f, 0.f, 0.f};

#define STAGE256(P, kt)                                                            \
  do {                                                                             \
    _Pragma("unroll") for (int c = 0; c < 4; ++c)                                  \
      gload_lds16(Asrc + (size_t)c * 64 * DM + (kt),                               \
                  (void*)(sm + (P) * 32768 + c * 4096 + w * 512));                 \
    _Pragma("unroll") for (int c = 0; c < 4; ++c)                                  \
      gload_lds16(Bsrc + (size_t)c * 64 * DM + (kt),                               \
                  (void*)(sm + (P) * 32768 + 16384 + c * 4096 + w * 512));         \
  } while (0)

  STAGE256(0, 0);
  __syncthreads();
  for (int kt16 = 0; kt16 < 16; ++kt16) {
    int P = kt16 & 1;
    if (kt16 < 15) STAGE256(P ^ 1, (kt16 + 1) * 64);
    const __bf16* A0 = sm + P * 32768;
    const __bf16* B0 = A0 + 16384;
#pragma unroll
    for (int ks = 0; ks < 2; ++ks) {
      bf16x8 fa[8], fb[4];
      int ck = (((ks * 4 + l4) ^ l7) << 3);
#pragma unroll
      for (int mi = 0; mi < 8; ++mi)
        fa[mi] = *(const bf16x8*)(A0 + (wm * 128 + mi * 16 + l15) * 64 + ck);
#pragma unroll
      for (int ni = 0; ni < 4; ++ni)
        fb[ni] = *(const bf16x8*)(B0 + (wn * 64 + ni * 16 + l15) * 64 + ck);
#pragma unroll
      for (int mi = 0; mi < 8; ++mi)
#pragma unroll
        for (int ni = 0; ni < 4; ++ni)
          acc[mi][ni] = __builtin_amdgcn_mfma_f32_16x16x32_bf16(fa[mi], fb[ni], acc[mi][ni], 0, 0, 0);
    }
    __syncthreads();
  }
#undef STAGE256

  // ---- epilogue: each wave's 64-col stripe == one head ----
  const int colbase = n0 + wn * 64;
  float bb[4];
#pragma unroll
  for (int ni = 0; ni < 4; ++ni) bb[ni] = biasP[colbase + ni * 16 + l15];

  if (colbase < 2048) {
    // Q or K: per-head L2 normalize in fp32, then write bf16
    unsigned short* dstp = (colbase < 1024) ? Qb : Kb;
    int coff = (colbase < 1024) ? colbase : (colbase - 1024);
#pragma unroll
    for (int mi = 0; mi < 8; ++mi)
#pragma unroll
      for (int e = 0; e < 4; ++e) {
        float v[4]; float ssq = 0.f;
#pragma unroll
        for (int ni = 0; ni < 4; ++ni) { v[ni] = acc[mi][ni][e] + bb[ni]; ssq += v[ni] * v[ni]; }
        ssq += __shfl_xor(ssq, 1);
        ssq += __shfl_xor(ssq, 2);
        ssq += __shfl_xor(ssq, 4);
        ssq += __shfl_xor(ssq, 8);       // full 64-col head (16 lanes x 4)
        float sc = 1.0f / fmaxf(sqrtf(ssq), 1e-12f);
        int row = m0 + wm * 128 + mi * 16 + 4 * l4 + e;
#pragma unroll
        for (int ni = 0; ni < 4; ++ni)
          dstp[(size_t)row * DM + coff + ni * 16 + l15] = f2bf(v[ni] * sc);
      }
  } else {
    // V: multiply by sigmoid(w-logit) of this row/head
    int hv = (colbase - 2048) >> 6;
    int coff = colbase - 2048;
#pragma unroll
    for (int mi = 0; mi < 8; ++mi)
#pragma unroll
      for (int e = 0; e < 4; ++e) {
        int row = m0 + wm * 128 + mi * 16 + 4 * l4 + e;
        float wgt = sigm(WRf[(size_t)row * 32 + hv]);
#pragma unroll
        for (int ni = 0; ni < 4; ++ni)
          Vb[(size_t)row * DM + coff + ni * 16 + l15] = f2bf((acc[mi][ni][e] + bb[ni]) * wgt);
      }
  }
}

// ---------------- gemm_A split-K: partial[sk][bn] over s in [sk*1024,(sk+1)*1024) ----
__global__ __launch_bounds__(256, 2) void k_gemm_A(const unsigned short* __restrict__ Kb,
                                                   const unsigned short* __restrict__ Vb,
                                                   float* __restrict__ Apart) {
  __shared__ __bf16 sK[64 * 64];
  __shared__ __bf16 sV[64 * 64];
  int t = threadIdx.x, lane = t & 63, wid = t >> 6;
  int bn = blockIdx.x & 127, sk = blockIdx.x >> 7;
  int b = bn >> 4, n = bn & 15;
  f32x4 acc[4];
#pragma unroll
  for (int j = 0; j < 4; j++) acc[j] = (f32x4){0.f, 0.f, 0.f, 0.f};
  int lrow = lane >> 3, lcol = (lane & 7) * 8;

  for (int st = sk * 1024; st < (sk + 1) * 1024; st += 64) {
#pragma unroll
    for (int c = 0; c < 2; c++) {
      int r0 = wid * 16 + c * 8;
      size_t g = ((size_t)(st + r0 + lrow) * 8 + b) * DM + n * 64 + lcol;
      gload_lds16(Kb + g, (void*)(sK + r0 * 64));
      gload_lds16(Vb + g, (void*)(sV + r0 * 64));
    }
    __syncthreads();
#pragma unroll
    for (int kk = 0; kk < 64; kk += 32) {
      bf16x8 av, bv[4];
#pragma unroll
      for (int e = 0; e < 8; e++)
        av[e] = sV[(kk + 8 * (lane >> 4) + e) * 64 + wid * 16 + (lane & 15)];
#pragma unroll
      for (int jn = 0; jn < 4; jn++)
#pragma unroll
        for (int e = 0; e < 8; e++)
          bv[jn][e] = sK[(kk + 8 * (lane >> 4) + e) * 64 + jn * 16 + (lane & 15)];
#pragma unroll
      for (int jn = 0; jn < 4; jn++)
        acc[jn] = __builtin_amdgcn_mfma_f32_16x16x32_bf16(av, bv[jn], acc[jn], 0, 0, 0);
    }
    __syncthreads();
  }
  float* Ap = Apart + (size_t)(sk * 128 + bn) * 4096;
#pragma unroll
  for (int jn = 0; jn < 4; jn++) {
#pragma unroll
    for (int e = 0; e < 4; e++) {
      int i = wid * 16 + 4 * (lane >> 4) + e;
      int j = jn * 16 + (lane & 15);
      Ap[i * 64 + j] = acc[jn][e];
    }
  }
}

// ---------------- reduce split-K partials -> Aout (fp32) + Abf (bf16) ----------------
__global__ __launch_bounds__(256) void k_reduceA(const float* __restrict__ Apart,
                                                 float* __restrict__ Aout,
                                                 unsigned short* __restrict__ Abf) {
  int bn = blockIdx.x, t = threadIdx.x;
  size_t base = (size_t)bn * 4096 + t * 16;
#pragma unroll
  for (int j = 0; j < 4; ++j) {
    f32x4 x = *(const f32x4*)(Apart + base + j * 4);
    f32x4 y = *(const f32x4*)(Apart + (size_t)128 * 4096 + base + j * 4);
    x += y;
    *(f32x4*)(Aout + base + j * 4) = x;
    u16x4 o;
    o[0] = f2bf(x[0]); o[1] = f2bf(x[1]); o[2] = f2bf(x[2]); o[3] = f2bf(x[3]);
    *(u16x4*)(Abf + base + j * 4) = o;
  }
}

// ---------------- out2[row, n*64+i] = r * sum_j qhat[row, n*64+j]*A[bn,i,j] ----------------
__global__ __launch_bounds__(256, 2) void k_gemm_o2(const unsigned short* __restrict__ Qb,
                                                    const unsigned short* __restrict__ Abf,
                                                    const float* __restrict__ WRf,
                                                    unsigned short* __restrict__ Ob) {
  __shared__ __bf16 sQ[128 * 64];
  __shared__ __bf16 sA[64 * 64];
  int t = threadIdx.x, lane = t & 63, wid = t >> 6;
  int bn = blockIdx.x & 127, stile = blockIdx.x >> 7;
  int b = bn >> 4, n = bn & 15;
  int s0 = stile * 128;
  int lrow = lane >> 3, lcol = (lane & 7) * 8;
#pragma unroll
  for (int c = 0; c < 4; c++) {
    int r0 = wid * 32 + c * 8;
    gload_lds16(Qb + ((size_t)(s0 + r0 + lrow) * 8 + b) * DM + n * 64 + lcol,
                (void*)(sQ + r0 * 64));
  }
#pragma unroll
  for (int c = 0; c < 2; c++) {
    int r0 = wid * 16 + c * 8;
    gload_lds16(Abf + (size_t)bn * 4096 + (size_t)(r0 + lrow) * 64 + lcol,
                (void*)(sA + r0 * 64));
  }
  __syncthreads();
  f32x4 acc[2][4];
#pragma unroll
  for (int i = 0; i < 2; i++)
#pragma unroll
    for (int j = 0; j < 4; j++) acc[i][j] = (f32x4){0.f, 0.f, 0.f, 0.f};
#pragma unroll
  for (int kk = 0; kk < 64; kk += 32) {
    bf16x8 aq[2], bA[4];
#pragma unroll
    for (int mi = 0; mi < 2; mi++)
      aq[mi] = *(const bf16x8*)(sQ + (wid * 32 + mi * 16 + (lane & 15)) * 64 + kk + 8 * (lane >> 4));
#pragma unroll
    for (int ni = 0; ni < 4; ni++)
      bA[ni] = *(const bf16x8*)(sA + (ni * 16 + (lane & 15)) * 64 + kk + 8 * (lane >> 4));
#pragma unroll
    for (int mi = 0; mi < 2; mi++)
#pragma unroll
      for (int ni = 0; ni < 4; ni++)
        acc[mi][ni] = __builtin_amdgcn_mfma_f32_16x16x32_bf16(aq[mi], bA[ni], acc[mi][ni], 0, 0, 0);
  }
#pragma unroll
  for (int mi = 0; mi < 2; mi++) {
#pragma unroll
    for (int e = 0; e < 4; e++) {
      int srow = wid * 32 + mi * 16 + 4 * (lane >> 4) + e;
      size_t row = (size_t)(s0 + srow) * 8 + b;
      float rv = sigm(WRf[row * 32 + 16 + n]);
#pragma unroll
      for (int ni = 0; ni < 4; ni++)
        Ob[row * DM + n * 64 + ni * 16 + (lane & 15)] = f2bf(acc[mi][ni][e] * rv);
    }
  }
}

// ---------------- final projection: Out = Ob @ Wo^T + bo (128^2 m97) ----------------
__global__ __launch_bounds__(256, 2) void k_gemm_out(const unsigned short* __restrict__ Ob,
                                                     const unsigned short* __restrict__ Wob,
                                                     const float* __restrict__ bo,
                                                     float* __restrict__ Out) {
  __shared__ __bf16 smA[128 * 64];
  __shared__ __bf16 smB[128 * 64];
  int t = threadIdx.x, lane = t & 63, wid = t >> 6;
  int m0 = (blockIdx.x & 127) * 128;
  int n0 = (blockIdx.x >> 7) * 128;
  int wr = wid >> 1, wc = wid & 1;
  f32x4 acc[4][4];
#pragma unroll
  for (int i = 0; i < 4; i++)
#pragma unroll
    for (int j = 0; j < 4; j++) acc[i][j] = (f32x4){0.f, 0.f, 0.f, 0.f};
  int srow = wid * 32;
  int lrow = lane >> 3, lcol = (lane & 7) * 8;

  for (int kt = 0; kt < DM; kt += 64) {
#pragma unroll
    for (int c = 0; c < 4; c++) {
      int r = srow + c * 8 + lrow;
      gload_lds16(Ob + (size_t)(m0 + r) * DM + kt + lcol, (void*)(smA + (srow + c * 8) * 64));
      gload_lds16(Wob + (size_t)(n0 + r) * DM + kt + lcol, (void*)(smB + (srow + c * 8) * 64));
    }
    __syncthreads();
#pragma unroll
    for (int kk = 0; kk < 64; kk += 32) {
      bf16x8 fa[4], fb[4];
#pragma unroll
      for (int mi = 0; mi < 4; mi++)
        fa[mi] = *(const bf16x8*)(smA + (wr * 64 + mi * 16 + (lane & 15)) * 64 + kk + 8 * (lane >> 4));
#pragma unroll
      for (int ni = 0; ni < 4; ni++)
        fb[ni] = *(const bf16x8*)(smB + (wc * 64 + ni * 16 + (lane & 15)) * 64 + kk + 8 * (lane >> 4));
#pragma unroll
      for (int mi = 0; mi < 4; mi++)
#pragma unroll
        for (int ni = 0; ni < 4; ni++)
          acc[mi][ni] = __builtin_amdgcn_mfma_f32_16x16x32_bf16(fa[mi], fb[ni], acc[mi][ni], 0, 0, 0);
    }
    __syncthreads();
  }
#pragma unroll
  for (int mi = 0; mi < 4; mi++) {
#pragma unroll
    for (int e = 0; e < 4; e++) {
      int row = m0 + wr * 64 + mi * 16 + 4 * (lane >> 4) + e;
#pragma unroll
      for (int ni = 0; ni < 4; ni++) {
        int col = n0 + wc * 64 + ni * 16 + (lane & 15);
        Out[(size_t)row * DM + col] = acc[mi][ni][e] + bo[col];
      }
    }
  }
}

// ---------------------------------------------------------------------------
extern "C" void kernel_launch(void* const* d_in, const int* in_sizes, int n_in,
                              void* d_out, int out_size, void* d_ws, size_t ws_size,
                              hipStream_t stream) {
  (void)in_sizes; (void)n_in; (void)out_size; (void)ws_size;
  const float* X  = (const float*)d_in[0];
  const float* Wq = (const float*)d_in[1];  const float* bq = (const float*)d_in[2];
  const float* Wk = (const float*)d_in[3];  const float* bk = (const float*)d_in[4];
  const float* Wv = (const float*)d_in[5];  const float* bv = (const float*)d_in[6];
  const float* Wo = (const float*)d_in[7];  const float* bo = (const float*)d_in[8];
  const float* Ww = (const float*)d_in[9];  const float* bw = (const float*)d_in[10];
  const float* Wr = (const float*)d_in[11]; const float* br = (const float*)d_in[12];

  char* ws = (char*)d_ws;
  // Apart (4,194,304) and Abf (1,048,576) alias dead Wpack region [0, 6,291,456).
  unsigned short* Wpack = (unsigned short*)(ws + 0);            // 6,291,456
  float*          Apart = (float*)(ws + 0);                     // alias (after qkv3)
  unsigned short* Abf   = (unsigned short*)(ws + 4194304);      // alias (after qkv3)
  float*          biasP = (float*)(ws + 6291456);               // 12,288
  unsigned short* WRw   = (unsigned short*)(ws + 6303744);      // 65,536
  float*          biasWR= (float*)(ws + 6369280);               // 128
  unsigned short* Wob   = (unsigned short*)(ws + 6369408);      // 2,097,152
  unsigned short* Xb    = (unsigned short*)(ws + 8466560);      // 33,554,432
  unsigned short* Ob    = Xb;                                   // alias (after qkv3)
  unsigned short* Qb    = (unsigned short*)(ws + 42020992);     // 33,554,432
  unsigned short* Kb    = (unsigned short*)(ws + 75575424);     // 33,554,432
  unsigned short* Vb    = (unsigned short*)(ws + 109129856);    // 33,554,432
  float*          WRf   = (float*)(ws + 142684288);             // 2,097,152 -> 144,781,440

  float* Out0 = (float*)d_out;
  float* Aout = Out0 + (size_t)ROWS * DM;   // second tuple output

  k_cast_x<<<dim3(8192), dim3(256), 0, stream>>>(X, Xb);
  k_pack_w<<<dim3(4128), dim3(256), 0, stream>>>(Wq, Wk, Wv, Wo, Ww, Wr,
                                                 bq, bk, bv, bw, br,
                                                 Wpack, biasP, WRw, biasWR, Wob);
  k_wr<<<dim3(128), dim3(256), 0, stream>>>(Xb, WRw, biasWR, WRf);
  k_gemm_qkv3<<<dim3(768), dim3(512), 0, stream>>>(Xb, Wpack, biasP, WRf, Qb, Kb, Vb);
  k_gemm_A<<<dim3(256), dim3(256), 0, stream>>>(Kb, Vb, Apart);
  k_reduceA<<<dim3(128), dim3(256), 0, stream>>>(Apart, Aout, Abf);
  k_gemm_o2<<<dim3(2048), dim3(256), 0, stream>>>(Qb, Abf, WRf, Ob);
  k_gemm_out<<<dim3(1024), dim3(256), 0, stream>>>(Ob, Wob, bo, Out0);
}